// Round 1
// baseline (5350.830 us; speedup 1.0000x reference)
//
#include <hip/hip_runtime.h>
#include <cmath>

// ---------------------------------------------------------------------------
// ACT classifier (B=65536, D=512, H=256, C=100, T=10), fp32 faithful version.
// Round 1: correctness baseline. All GEMMs on vector ALU (no fp32 MFMA on
// CDNA4); ACT branch path must stay ~1e-6 close to reference to avoid
// halting-branch flips (absmax 1.0 vs threshold 0.08).
// ---------------------------------------------------------------------------

namespace {
constexpr int B = 65536, D = 512, H = 256, C = 100, T = 10;
constexpr int H3 = 3 * H; // 768

// output layout (flat float elements, in reference return order)
constexpr long OUT_LOGITS = 0;
constexpr long OUT_PONDER = (long)B * C;            // 6,553,600
constexpr long OUT_NUP    = OUT_PONDER + 1;         // 6,553,601
constexpr long OUT_HSEQ   = OUT_NUP + B;            // 6,619,137
constexpr long OUT_HALT   = OUT_HSEQ + (long)B * T * H;  // 174,391,297
constexpr long OUT_LSEQ   = OUT_HALT + (long)B * T;      // 175,046,657

// workspace layout (float elements)
constexpr long WS_XP   = 0;                         // x_proj [B][768]
constexpr long WS_WTIH = WS_XP + (long)B * H3;      // W_ih^T [512][768]
constexpr long WS_WTHH = WS_WTIH + (long)D * H3;    // W_hh^T [256][768]
constexpr long WS_WTRO = WS_WTHH + (long)H * H3;    // W_ro^T [256][100]
constexpr long WS_SW   = WS_WTRO + (long)H * C;     // step_w [B][T]
constexpr long WS_CUM  = WS_SW + (long)B * T;
constexpr long WS_REM  = WS_CUM + B;
constexpr long WS_NUP  = WS_REM + B;
} // namespace

__device__ __forceinline__ float sigmoidf_(float x) {
  if (x >= 0.f) { return 1.f / (1.f + expf(-x)); }
  float e = expf(x);
  return e / (1.f + e);
}

__device__ __forceinline__ void ld4(float* d, const float4* p) {
  float4 v = *p;
  d[0] = v.x; d[1] = v.y; d[2] = v.z; d[3] = v.w;
}

// ---------------------------------------------------------------------------
__global__ void k_transpose(const float* __restrict__ src, float* __restrict__ dst,
                            int R, int Cc) {
  int idx = blockIdx.x * 256 + threadIdx.x;
  if (idx >= R * Cc) return;
  int r = idx / Cc, c = idx - r * Cc;
  dst[(long)c * R + r] = src[idx];
}

__global__ void k_zero3(float* a, float* b, float* c) {
  int i = blockIdx.x * 256 + threadIdx.x;
  if (i < B) { a[i] = 0.f; b[i] = 0.f; c[i] = 0.f; }
}

// ---------------------------------------------------------------------------
// x_proj = x @ W_ih^T + b_ih   ([B,512] x [512,768])
// block: 32 rows, 256 threads = 4 row-groups x 64 col-groups.
// thread: 8 rows x 12 cols (cols = cg*4+q + gate*256).
__global__ __launch_bounds__(256, 2) void k_xproj(
    const float* __restrict__ x, const float* __restrict__ wt /*[512][768]*/,
    const float* __restrict__ b_ih, float* __restrict__ xp) {
  __shared__ __align__(16) float xs[32 * 20];       // [row][k] pad 20
  __shared__ __align__(16) float wt_s[16 * 768];    // [kk][col]
  const int tid = threadIdx.x;
  const int rg = tid >> 6;   // 0..3
  const int cg = tid & 63;   // 0..63
  const int b0 = blockIdx.x * 32;

  float acc[8][12];
#pragma unroll
  for (int j = 0; j < 8; ++j)
#pragma unroll
    for (int q = 0; q < 12; ++q) acc[j][q] = 0.f;

  for (int kc = 0; kc < 32; ++kc) {
    const int k0 = kc * 16;
    __syncthreads();
    // stage x chunk: 32 rows x 16 k
    {
      int idx = tid;
#pragma unroll
      for (int it = 0; it < 2; ++it) {
        int r = idx >> 4, kk = idx & 15;
        xs[r * 20 + kk] = x[(long)(b0 + r) * D + k0 + kk];
        idx += 256;
      }
    }
    // stage W chunk: 16 rows x 768 (contiguous in wt)
    {
      const float4* src = (const float4*)(wt + (long)k0 * H3);
      float4* dst = (float4*)wt_s;
#pragma unroll
      for (int it = 0; it < 12; ++it) dst[tid + it * 256] = src[tid + it * 256];
    }
    __syncthreads();
#pragma unroll
    for (int kk = 0; kk < 16; ++kk) {
      float wa[12];
      ld4(wa + 0, (const float4*)wt_s + kk * 192 + cg);
      ld4(wa + 4, (const float4*)wt_s + kk * 192 + 64 + cg);
      ld4(wa + 8, (const float4*)wt_s + kk * 192 + 128 + cg);
#pragma unroll
      for (int j = 0; j < 8; ++j) {
        float hv = xs[(rg * 8 + j) * 20 + kk];
#pragma unroll
        for (int q = 0; q < 12; ++q) acc[j][q] = fmaf(hv, wa[q], acc[j][q]);
      }
    }
  }
  // epilogue: + b_ih, store
#pragma unroll
  for (int i = 0; i < 3; ++i) {
    float bi[4];
    ld4(bi, (const float4*)b_ih + i * 64 + cg);
#pragma unroll
    for (int j = 0; j < 8; ++j) {
      long b = b0 + rg * 8 + j;
      float4 v = make_float4(acc[j][i * 4 + 0] + bi[0], acc[j][i * 4 + 1] + bi[1],
                             acc[j][i * 4 + 2] + bi[2], acc[j][i * 4 + 3] + bi[3]);
      ((float4*)xp)[b * 192 + i * 64 + cg] = v;
    }
  }
}

// ---------------------------------------------------------------------------
// One fused ponder step.
__global__ __launch_bounds__(256, 2) void k_step(
    const float* __restrict__ wt_hh /*[256][768]*/, const float* __restrict__ xp,
    const float* __restrict__ b_hh, const float* __restrict__ w_halt,
    const float* __restrict__ b_halt, float* __restrict__ out,
    float* __restrict__ cumb, float* __restrict__ remb, float* __restrict__ nupb,
    float* __restrict__ swb, int t) {
  __shared__ __align__(16) float hs[32 * 260];      // [row][k] pad 260
  __shared__ __align__(16) float wt_s[8 * 768];     // [kk][col]
  __shared__ float sh_halt[32];
  const int tid = threadIdx.x;
  const int rg = tid >> 6;   // 0..3 (one wave each)
  const int cg = tid & 63;
  const int b0 = blockIdx.x * 32;

  // stage h (previous step) or zeros
  if (t == 0) {
#pragma unroll
    for (int it = 0; it < 33; ++it) {
      int idx = tid + it * 256;
      if (idx < 32 * 260) hs[idx] = 0.f;
    }
  } else {
#pragma unroll
    for (int i = 0; i < 32; ++i)
      hs[i * 260 + tid] = out[OUT_HSEQ + ((long)(b0 + i) * T + (t - 1)) * H + tid];
  }

  float acc[8][12];
#pragma unroll
  for (int j = 0; j < 8; ++j)
#pragma unroll
    for (int q = 0; q < 12; ++q) acc[j][q] = 0.f;

  if (t > 0) {
    for (int kc = 0; kc < 32; ++kc) {
      const int k0 = kc * 8;
      __syncthreads();
      {
        const float4* src = (const float4*)(wt_hh + (long)k0 * H3);
        float4* dst = (float4*)wt_s;
#pragma unroll
        for (int it = 0; it < 6; ++it) dst[tid + it * 256] = src[tid + it * 256];
      }
      __syncthreads();
#pragma unroll
      for (int kk = 0; kk < 8; ++kk) {
        float wa[12];
        ld4(wa + 0, (const float4*)wt_s + kk * 192 + cg);
        ld4(wa + 4, (const float4*)wt_s + kk * 192 + 64 + cg);
        ld4(wa + 8, (const float4*)wt_s + kk * 192 + 128 + cg);
#pragma unroll
        for (int j = 0; j < 8; ++j) {
          float hv = hs[(rg * 8 + j) * 260 + k0 + kk];
#pragma unroll
          for (int q = 0; q < 12; ++q) acc[j][q] = fmaf(hv, wa[q], acc[j][q]);
        }
      }
    }
  } else {
    __syncthreads(); // make zeroed hs visible
  }

  // epilogue: gates, h_new, halt, ACT bookkeeping
  const float bhalt = b_halt[0];
  float bhr[4], bhz[4], bhn[4], whv[4];
  ld4(bhr, (const float4*)b_hh + cg);
  ld4(bhz, (const float4*)b_hh + 64 + cg);
  ld4(bhn, (const float4*)b_hh + 128 + cg);
  ld4(whv, (const float4*)w_halt + cg);
  const float cth = 0.99f;

#pragma unroll
  for (int j = 0; j < 8; ++j) {
    const int row = rg * 8 + j;
    const long b = b0 + row;
    float xr[4], xz[4], xn[4], hold[4];
    ld4(xr, (const float4*)xp + b * 192 + cg);
    ld4(xz, (const float4*)xp + b * 192 + 64 + cg);
    ld4(xn, (const float4*)xp + b * 192 + 128 + cg);
    ld4(hold, (const float4*)(hs + row * 260) + cg);
    float hn[4];
    float hd = 0.f;
#pragma unroll
    for (int q = 0; q < 4; ++q) {
      float rr = sigmoidf_(xr[q] + acc[j][q] + bhr[q]);
      float zz = sigmoidf_(xz[q] + acc[j][4 + q] + bhz[q]);
      float nn = tanhf(xn[q] + rr * (acc[j][8 + q] + bhn[q]));
      float hv = (1.f - zz) * nn + zz * hold[q];
      hn[q] = hv;
      hd = fmaf(hv, whv[q], hd);
    }
    ((float4*)(hs + row * 260))[cg] = make_float4(hn[0], hn[1], hn[2], hn[3]);
    // 64-lane reduce (all lanes of this wave share the same 8 rows)
#pragma unroll
    for (int m = 1; m < 64; m <<= 1) hd += __shfl_xor(hd, m, 64);
    float halt = sigmoidf_(hd + bhalt);
    if (cg == 0) {
      sh_halt[row] = halt;
      float cum = cumb[b];
      float still = (cum < cth) ? 1.f : 0.f;
      float nh = halt * still;
      float would = ((cum + nh) > cth) ? 1.f : 0.f;
      float rema = (1.f - cum) * would * still;
      float swv = nh * (1.f - would) + rema;
      cumb[b] = cum + swv;
      remb[b] += rema;
      nupb[b] += still;
      swb[b * T + t] = swv;
    }
  }
  __syncthreads();
  // write h_seq (coalesced) and halt_seq
#pragma unroll
  for (int i = 0; i < 32; ++i)
    out[OUT_HSEQ + ((long)(b0 + i) * T + t) * H + tid] = hs[i * 260 + tid];
  if (tid < 32) out[OUT_HALT + (long)(b0 + tid) * T + t] = sh_halt[tid];
}

// ---------------------------------------------------------------------------
// logits_seq = h_seq @ W_ro^T + b_ro    ([B*T,256] x [256,100])
__global__ __launch_bounds__(256, 3) void k_lseq(
    const float* __restrict__ wro_t /*[256][100]*/, const float* __restrict__ b_ro,
    const float* __restrict__ hseq, float* __restrict__ lseq) {
  __shared__ __align__(16) float hsl[32 * 260];
  __shared__ __align__(16) float wr[32 * 128];
  const int tid = threadIdx.x;
  const int rg = tid >> 5;  // 0..7 -> 4 rows each
  const int cg = tid & 31;
  const long m0 = (long)blockIdx.x * 32;

#pragma unroll
  for (int i = 0; i < 32; ++i) hsl[i * 260 + tid] = hseq[(m0 + i) * H + tid];

  float acc[4][4];
#pragma unroll
  for (int j = 0; j < 4; ++j)
#pragma unroll
    for (int i = 0; i < 4; ++i) acc[j][i] = 0.f;

  for (int kc = 0; kc < 8; ++kc) {
    const int k0 = kc * 32;
    __syncthreads();
#pragma unroll
    for (int it = 0; it < 16; ++it) {
      int idx = tid + it * 256;
      int kk = idx >> 7, c = idx & 127;
      wr[idx] = (c < C) ? wro_t[(k0 + kk) * C + c] : 0.f;
    }
    __syncthreads();
#pragma unroll
    for (int kk = 0; kk < 32; ++kk) {
      const int k = k0 + kk;
      float w0 = wr[kk * 128 + cg], w1 = wr[kk * 128 + 32 + cg];
      float w2 = wr[kk * 128 + 64 + cg], w3 = wr[kk * 128 + 96 + cg];
#pragma unroll
      for (int j = 0; j < 4; ++j) {
        float hv = hsl[(rg * 4 + j) * 260 + k];
        acc[j][0] = fmaf(hv, w0, acc[j][0]);
        acc[j][1] = fmaf(hv, w1, acc[j][1]);
        acc[j][2] = fmaf(hv, w2, acc[j][2]);
        acc[j][3] = fmaf(hv, w3, acc[j][3]);
      }
    }
  }
#pragma unroll
  for (int i = 0; i < 4; ++i) {
    int col = cg + i * 32;
    if (col < C) {
      float br = b_ro[col];
#pragma unroll
      for (int j = 0; j < 4; ++j)
        lseq[(m0 + rg * 4 + j) * C + col] = acc[j][i] + br;
    }
  }
}

// ---------------------------------------------------------------------------
// logits[b,c] = b_ro[c] + sum_t sw[b,t]*(lseq[b,t,c]-b_ro[c]);  n_updates copy
__global__ void k_logits(const float* __restrict__ lseq, const float* __restrict__ swb,
                         const float* __restrict__ b_ro, const float* __restrict__ nupb,
                         float* __restrict__ out) {
  const long b = blockIdx.x;
  const int tid = threadIdx.x;
  if (tid < C) {
    float br = b_ro[tid];
    float s = br;
#pragma unroll
    for (int t = 0; t < T; ++t) {
      float sw = swb[b * T + t];
      s = fmaf(sw, lseq[(b * T + t) * C + tid] - br, s);
    }
    out[OUT_LOGITS + b * C + tid] = s;
  } else if (tid == C) {
    out[OUT_NUP + b] = nupb[b];
  }
}

// ---------------------------------------------------------------------------
__global__ void k_ponder(const float* __restrict__ nupb, const float* __restrict__ remb,
                         float* __restrict__ out) {
  __shared__ float sm[4];
  float s = 0.f;
  for (int i = threadIdx.x; i < B; i += 256) s += nupb[i] + remb[i];
#pragma unroll
  for (int m = 1; m < 64; m <<= 1) s += __shfl_xor(s, m, 64);
  int w = threadIdx.x >> 6;
  if ((threadIdx.x & 63) == 0) sm[w] = s;
  __syncthreads();
  if (threadIdx.x == 0)
    out[OUT_PONDER] = (sm[0] + sm[1] + sm[2] + sm[3]) * (1.f / (float)B);
}

// ---------------------------------------------------------------------------
extern "C" void kernel_launch(void* const* d_in, const int* in_sizes, int n_in,
                              void* d_out, int out_size, void* d_ws, size_t ws_size,
                              hipStream_t stream) {
  const float* x      = (const float*)d_in[0];
  const float* W_ih   = (const float*)d_in[1];
  const float* W_hh   = (const float*)d_in[2];
  const float* b_ih   = (const float*)d_in[3];
  const float* b_hh   = (const float*)d_in[4];
  const float* W_halt = (const float*)d_in[5];
  const float* b_halt = (const float*)d_in[6];
  const float* W_ro   = (const float*)d_in[7];
  const float* b_ro   = (const float*)d_in[8];
  float* out = (float*)d_out;
  float* ws  = (float*)d_ws;

  float* xp   = ws + WS_XP;
  float* wtih = ws + WS_WTIH;
  float* wthh = ws + WS_WTHH;
  float* wtro = ws + WS_WTRO;
  float* swb  = ws + WS_SW;
  float* cum  = ws + WS_CUM;
  float* rem  = ws + WS_REM;
  float* nup  = ws + WS_NUP;

  k_transpose<<<(H3 * D + 255) / 256, 256, 0, stream>>>(W_ih, wtih, H3, D);
  k_transpose<<<(H3 * H + 255) / 256, 256, 0, stream>>>(W_hh, wthh, H3, H);
  k_transpose<<<(C * H + 255) / 256, 256, 0, stream>>>(W_ro, wtro, C, H);
  k_zero3<<<B / 256, 256, 0, stream>>>(cum, rem, nup);

  k_xproj<<<B / 32, 256, 0, stream>>>(x, wtih, b_ih, xp);

  for (int t = 0; t < T; ++t)
    k_step<<<B / 32, 256, 0, stream>>>(wthh, xp, b_hh, W_halt, b_halt, out, cum,
                                       rem, nup, swb, t);

  k_lseq<<<(B * T) / 32, 256, 0, stream>>>(wtro, b_ro, out + OUT_HSEQ, out + OUT_LSEQ);
  k_logits<<<B, 128, 0, stream>>>(out + OUT_LSEQ, swb, b_ro, nup, out);
  k_ponder<<<1, 256, 0, stream>>>(nup, rem, out);
}

// Round 2
// 2988.025 us; speedup vs baseline: 1.7908x; 1.7908x over previous
//
#include <hip/hip_runtime.h>
#include <cmath>

// ---------------------------------------------------------------------------
// ACT classifier (B=65536, D=512, H=256, C=100, T=10).
// Round 2: MFMA bf16 triple-split (hi/mid/lo, 6 products) for all GEMMs.
// x = hi+mid+lo is EXACT for fp32 (24 = 3x8 mantissa bits); dropped cross
// terms ~2^-26 -> fp32-reorder-class error, safe for the ACT branch at 0.99.
// Pipeline: prep-split W -> xproj GEMM -> 10x GRU GEMM+gates (no halt logic;
// h is ACT-independent) -> augmented readout GEMM (100 logit cols + halt col)
// -> per-row ACT chain -> logits recombine -> ponder reduce.
// ---------------------------------------------------------------------------

namespace {
constexpr int B = 65536, D = 512, H = 256, C = 100, T = 10;
constexpr int H3 = 768;

// output layout (flat float elements, reference return order)
constexpr long OUT_LOGITS = 0;
constexpr long OUT_PONDER = (long)B * C;
constexpr long OUT_NUP    = OUT_PONDER + 1;
constexpr long OUT_HSEQ   = OUT_NUP + B;
constexpr long OUT_HALT   = OUT_HSEQ + (long)B * T * H;
constexpr long OUT_LSEQ   = OUT_HALT + (long)B * T;

// workspace layout (float units)
constexpr long NIH  = (long)H3 * D;   // 393216  W_ih elems
constexpr long NHH  = (long)H3 * H;   // 196608  W_hh elems
constexpr long NAUG = 112L * H;       // 28672   augmented readout elems
constexpr long WS_XP   = 0;                         // x_proj [B][768] f32
constexpr long WS_W    = WS_XP + (long)B * H3;      // ushort region
constexpr long W_USH   = 3 * (NIH + NHH + NAUG);    // 1,855,488 ushorts
constexpr long WS_HL   = WS_W + (W_USH + 1) / 2;    // halt-logits, aliased w/ step_w [B][T]
constexpr long WS_NUPB = WS_HL + (long)B * T;
constexpr long WS_REMB = WS_NUPB + B;
} // namespace

typedef __attribute__((ext_vector_type(8))) short bf8;
typedef __attribute__((ext_vector_type(4))) float f4;
#define MFMA __builtin_amdgcn_mfma_f32_16x16x32_bf16

// 6-product triple-split accumulate, smallest terms first
#define PROD6(a, Ah, Am, Al, Bh, Bm, Bl)                                       \
  a = MFMA(Al, Bh, a, 0, 0, 0);                                                \
  a = MFMA(Am, Bm, a, 0, 0, 0);                                                \
  a = MFMA(Ah, Bl, a, 0, 0, 0);                                                \
  a = MFMA(Am, Bh, a, 0, 0, 0);                                                \
  a = MFMA(Ah, Bm, a, 0, 0, 0);                                                \
  a = MFMA(Ah, Bh, a, 0, 0, 0);

__device__ __forceinline__ ushort f2bf(float f) {
  unsigned u = __float_as_uint(f);
  u = (u + 0x7FFFu + ((u >> 16) & 1u)) >> 16;  // RNE
  return (ushort)u;
}
__device__ __forceinline__ float bf2f(ushort b) {
  return __uint_as_float(((unsigned)b) << 16);
}
__device__ __forceinline__ float sigmoidf_(float x) {
  if (x >= 0.f) { return 1.f / (1.f + expf(-x)); }
  float e = expf(x);
  return e / (1.f + e);
}

// ---------------------------------------------------------------------------
// split weights into hi/mid/lo bf16 (original [outcol][k] layout == B-frag layout)
__global__ void k_prep(const float* __restrict__ wih_s, const float* __restrict__ whh_s,
                       const float* __restrict__ wro, const float* __restrict__ whalt,
                       ushort* __restrict__ wr) {
  long idx = (long)blockIdx.x * 256 + threadIdx.x;
  if (idx < NIH) {
    float x = wih_s[idx];
    ushort h = f2bf(x); float fh = bf2f(h);
    ushort m = f2bf(x - fh); float fm = bf2f(m);
    ushort l = f2bf(x - fh - fm);
    wr[idx] = h; wr[NIH + idx] = m; wr[2 * NIH + idx] = l;
  }
  if (idx < NHH) {
    float x = whh_s[idx];
    ushort h = f2bf(x); float fh = bf2f(h);
    ushort m = f2bf(x - fh); float fm = bf2f(m);
    ushort l = f2bf(x - fh - fm);
    long b = 3 * NIH;
    wr[b + idx] = h; wr[b + NHH + idx] = m; wr[b + 2 * NHH + idx] = l;
  }
  if (idx < NAUG) {
    int row = (int)(idx >> 8), k = (int)(idx & 255);
    float x = (row < C) ? wro[row * 256 + k] : ((row == C) ? whalt[k] : 0.f);
    ushort h = f2bf(x); float fh = bf2f(h);
    ushort m = f2bf(x - fh); float fm = bf2f(m);
    ushort l = f2bf(x - fh - fm);
    long b = 3 * (NIH + NHH);
    wr[b + idx] = h; wr[b + NAUG + idx] = m; wr[b + 2 * NAUG + idx] = l;
  }
}

// ---------------------------------------------------------------------------
// xp = x @ W_ih^T + b_ih.  Block: 128 rows x 64 hidden cols (192 proj cols as
// 3 gate strips).  4 waves, wave tile 128x48 (m=8 row-tiles, n=3 gate tiles).
__global__ __launch_bounds__(256, 2) void k_xproj(
    const float* __restrict__ x, const ushort* __restrict__ wih,
    const float* __restrict__ b_ih, float* __restrict__ xp) {
  __shared__ __align__(16) ushort As[3][128 * 40];
  __shared__ __align__(16) ushort Bs[3][192 * 40];
  const int tid = threadIdx.x;
  const int w = tid >> 6, l = tid & 63;
  const int lr = l & 15, lq = l >> 4;
  const int rb = blockIdx.x * 128;
  const int c0 = blockIdx.y * 64;

  f4 acc[8][3];
#pragma unroll
  for (int i = 0; i < 8; ++i)
#pragma unroll
    for (int g = 0; g < 3; ++g) acc[i][g] = (f4)0.f;

  for (int kc = 0; kc < 16; ++kc) {
    const int k0 = kc * 32;
    __syncthreads();
    // stage A (x rows, split to hi/mid/lo)
    {
      const int row = tid >> 1, kk0 = (tid & 1) * 16;
      const float* src = x + (long)(rb + row) * D + k0 + kk0;
#pragma unroll
      for (int i = 0; i < 4; ++i) {
        float4 v = ((const float4*)src)[i];
        float vv[4] = {v.x, v.y, v.z, v.w};
        ushort4 hh, mm, ll;
        ushort* hp = (ushort*)&hh; ushort* mp = (ushort*)&mm; ushort* lp = (ushort*)&ll;
#pragma unroll
        for (int c = 0; c < 4; ++c) {
          float xv = vv[c];
          ushort h = f2bf(xv); float fh = bf2f(h);
          ushort m = f2bf(xv - fh); float fm = bf2f(m);
          ushort lo = f2bf(xv - fh - fm);
          hp[c] = h; mp[c] = m; lp[c] = lo;
        }
        const int o = row * 40 + kk0 + i * 4;
        *(ushort4*)&As[0][o] = hh;
        *(ushort4*)&As[1][o] = mm;
        *(ushort4*)&As[2][o] = ll;
      }
    }
    // stage B (weight slices; [col][k] already fragment-ready)
#pragma unroll
    for (int it = 0; it < 3; ++it) {
      int idx = tid + it * 256;  // < 768
      int scol = idx >> 2, kg = idx & 3;
      int gcol = (scol >> 6) * 256 + c0 + (scol & 63);
#pragma unroll
      for (int a = 0; a < 3; ++a) {
        bf8 v = *(const bf8*)(wih + (long)a * NIH + (long)gcol * D + k0 + kg * 8);
        *(bf8*)&Bs[a][scol * 40 + kg * 8] = v;
      }
    }
    __syncthreads();
    bf8 Bf[3][3];
#pragma unroll
    for (int g = 0; g < 3; ++g)
#pragma unroll
      for (int a = 0; a < 3; ++a)
        Bf[g][a] = *(const bf8*)&Bs[a][(g * 64 + w * 16 + lr) * 40 + lq * 8];
#pragma unroll
    for (int i = 0; i < 8; ++i) {
      bf8 Ah = *(const bf8*)&As[0][(i * 16 + lr) * 40 + lq * 8];
      bf8 Am = *(const bf8*)&As[1][(i * 16 + lr) * 40 + lq * 8];
      bf8 Al = *(const bf8*)&As[2][(i * 16 + lr) * 40 + lq * 8];
#pragma unroll
      for (int g = 0; g < 3; ++g) {
        f4 a = acc[i][g];
        PROD6(a, Ah, Am, Al, Bf[g][0], Bf[g][1], Bf[g][2]);
        acc[i][g] = a;
      }
    }
  }
  const int ch = c0 + w * 16 + lr;
  float bi[3] = {b_ih[ch], b_ih[256 + ch], b_ih[512 + ch]};
#pragma unroll
  for (int i = 0; i < 8; ++i)
#pragma unroll
    for (int g = 0; g < 3; ++g)
#pragma unroll
      for (int reg = 0; reg < 4; ++reg) {
        long row = rb + i * 16 + lq * 4 + reg;
        xp[row * 768 + g * 256 + ch] = acc[i][g][reg] + bi[g];
      }
}

// ---------------------------------------------------------------------------
// One GRU step: h_proj GEMM (h_{t-1} @ W_hh^T) + gates. No halt logic.
__global__ __launch_bounds__(256, 2) void k_gru(
    const ushort* __restrict__ whh, const float* __restrict__ xp,
    const float* __restrict__ b_hh, float* __restrict__ out, int t) {
  __shared__ __align__(16) ushort As[3][128 * 40];
  __shared__ __align__(16) ushort Bs[3][192 * 40];
  const int tid = threadIdx.x;
  const int w = tid >> 6, l = tid & 63;
  const int lr = l & 15, lq = l >> 4;
  const int rb = blockIdx.x * 128;
  const int c0 = blockIdx.y * 64;

  f4 acc[8][3];
#pragma unroll
  for (int i = 0; i < 8; ++i)
#pragma unroll
    for (int g = 0; g < 3; ++g) acc[i][g] = (f4)0.f;

  if (t > 0) {
    for (int kc = 0; kc < 8; ++kc) {
      const int k0 = kc * 32;
      __syncthreads();
      {  // stage A = h_{t-1} rows from h_seq
        const int row = tid >> 1, kk0 = (tid & 1) * 16;
        const float* src = out + OUT_HSEQ + (long)(rb + row) * (T * H) +
                           (long)(t - 1) * H + k0 + kk0;
#pragma unroll
        for (int i = 0; i < 4; ++i) {
          float4 v = ((const float4*)src)[i];
          float vv[4] = {v.x, v.y, v.z, v.w};
          ushort4 hh, mm, ll;
          ushort* hp = (ushort*)&hh; ushort* mp = (ushort*)&mm; ushort* lp = (ushort*)&ll;
#pragma unroll
          for (int c = 0; c < 4; ++c) {
            float xv = vv[c];
            ushort h = f2bf(xv); float fh = bf2f(h);
            ushort m = f2bf(xv - fh); float fm = bf2f(m);
            ushort lo = f2bf(xv - fh - fm);
            hp[c] = h; mp[c] = m; lp[c] = lo;
          }
          const int o = row * 40 + kk0 + i * 4;
          *(ushort4*)&As[0][o] = hh;
          *(ushort4*)&As[1][o] = mm;
          *(ushort4*)&As[2][o] = ll;
        }
      }
#pragma unroll
      for (int it = 0; it < 3; ++it) {  // stage B (W_hh slices)
        int idx = tid + it * 256;
        int scol = idx >> 2, kg = idx & 3;
        int gcol = (scol >> 6) * 256 + c0 + (scol & 63);
#pragma unroll
        for (int a = 0; a < 3; ++a) {
          bf8 v = *(const bf8*)(whh + (long)a * NHH + (long)gcol * H + k0 + kg * 8);
          *(bf8*)&Bs[a][scol * 40 + kg * 8] = v;
        }
      }
      __syncthreads();
      bf8 Bf[3][3];
#pragma unroll
      for (int g = 0; g < 3; ++g)
#pragma unroll
        for (int a = 0; a < 3; ++a)
          Bf[g][a] = *(const bf8*)&Bs[a][(g * 64 + w * 16 + lr) * 40 + lq * 8];
#pragma unroll
      for (int i = 0; i < 8; ++i) {
        bf8 Ah = *(const bf8*)&As[0][(i * 16 + lr) * 40 + lq * 8];
        bf8 Am = *(const bf8*)&As[1][(i * 16 + lr) * 40 + lq * 8];
        bf8 Al = *(const bf8*)&As[2][(i * 16 + lr) * 40 + lq * 8];
#pragma unroll
        for (int g = 0; g < 3; ++g) {
          f4 a = acc[i][g];
          PROD6(a, Ah, Am, Al, Bf[g][0], Bf[g][1], Bf[g][2]);
          acc[i][g] = a;
        }
      }
    }
  }

  // epilogue: gates + h_new
  const int ch = c0 + w * 16 + lr;
  const float bhr = b_hh[ch], bhz = b_hh[256 + ch], bhn = b_hh[512 + ch];
#pragma unroll
  for (int i = 0; i < 8; ++i)
#pragma unroll
    for (int reg = 0; reg < 4; ++reg) {
      long row = rb + i * 16 + lq * 4 + reg;
      float xr = xp[row * 768 + ch];
      float xz = xp[row * 768 + 256 + ch];
      float xn = xp[row * 768 + 512 + ch];
      float ho = (t > 0) ? out[OUT_HSEQ + row * (T * H) + (long)(t - 1) * H + ch] : 0.f;
      float rr = sigmoidf_(xr + acc[i][0][reg] + bhr);
      float zz = sigmoidf_(xz + acc[i][1][reg] + bhz);
      float nn = tanhf(xn + rr * (acc[i][2][reg] + bhn));
      float hv = (1.f - zz) * nn + zz * ho;
      out[OUT_HSEQ + row * (T * H) + (long)t * H + ch] = hv;
    }
}

// ---------------------------------------------------------------------------
// Augmented readout: [B*T,256] x [256,112] -> lseq cols 0..99, halt-logit col 100.
// Block 128 rows x 112 cols; wave tile 32 rows (m=2) x 112 (n=7).
__global__ __launch_bounds__(256, 2) void k_lseq(
    const float* __restrict__ hseq, const ushort* __restrict__ waug,
    const float* __restrict__ b_ro, const float* __restrict__ b_halt,
    float* __restrict__ lseq, float* __restrict__ hl) {
  __shared__ __align__(16) ushort As[3][128 * 40];
  __shared__ __align__(16) ushort Bs[3][112 * 40];
  const int tid = threadIdx.x;
  const int w = tid >> 6, l = tid & 63;
  const int lr = l & 15, lq = l >> 4;
  const long mb = (long)blockIdx.x * 128;

  f4 acc[2][7];
#pragma unroll
  for (int i = 0; i < 2; ++i)
#pragma unroll
    for (int j = 0; j < 7; ++j) acc[i][j] = (f4)0.f;

  for (int kc = 0; kc < 8; ++kc) {
    const int k0 = kc * 32;
    __syncthreads();
    {  // stage A = h_seq rows (contiguous [m][256])
      const int row = tid >> 1, kk0 = (tid & 1) * 16;
      const float* src = hseq + (mb + row) * H + k0 + kk0;
#pragma unroll
      for (int i = 0; i < 4; ++i) {
        float4 v = ((const float4*)src)[i];
        float vv[4] = {v.x, v.y, v.z, v.w};
        ushort4 hh, mm, ll;
        ushort* hp = (ushort*)&hh; ushort* mp = (ushort*)&mm; ushort* lp = (ushort*)&ll;
#pragma unroll
        for (int c = 0; c < 4; ++c) {
          float xv = vv[c];
          ushort h = f2bf(xv); float fh = bf2f(h);
          ushort m = f2bf(xv - fh); float fm = bf2f(m);
          ushort lo = f2bf(xv - fh - fm);
          hp[c] = h; mp[c] = m; lp[c] = lo;
        }
        const int o = row * 40 + kk0 + i * 4;
        *(ushort4*)&As[0][o] = hh;
        *(ushort4*)&As[1][o] = mm;
        *(ushort4*)&As[2][o] = ll;
      }
    }
#pragma unroll
    for (int it = 0; it < 2; ++it) {  // stage B (augmented readout)
      int idx = tid + it * 256;
      if (idx < 448) {
        int scol = idx >> 2, kg = idx & 3;
#pragma unroll
        for (int a = 0; a < 3; ++a) {
          bf8 v = *(const bf8*)(waug + (long)a * NAUG + (long)scol * H + k0 + kg * 8);
          *(bf8*)&Bs[a][scol * 40 + kg * 8] = v;
        }
      }
    }
    __syncthreads();
    bf8 Af[2][3];
#pragma unroll
    for (int i = 0; i < 2; ++i)
#pragma unroll
      for (int a = 0; a < 3; ++a)
        Af[i][a] = *(const bf8*)&As[a][(w * 32 + i * 16 + lr) * 40 + lq * 8];
#pragma unroll
    for (int j = 0; j < 7; ++j) {
      bf8 Bh = *(const bf8*)&Bs[0][(j * 16 + lr) * 40 + lq * 8];
      bf8 Bm = *(const bf8*)&Bs[1][(j * 16 + lr) * 40 + lq * 8];
      bf8 Bl = *(const bf8*)&Bs[2][(j * 16 + lr) * 40 + lq * 8];
#pragma unroll
      for (int i = 0; i < 2; ++i) {
        f4 a = acc[i][j];
        PROD6(a, Af[i][0], Af[i][1], Af[i][2], Bh, Bm, Bl);
        acc[i][j] = a;
      }
    }
  }
#pragma unroll
  for (int j = 0; j < 7; ++j) {
    const int col = j * 16 + lr;
    const float bias = (col < C) ? b_ro[col] : ((col == C) ? b_halt[0] : 0.f);
#pragma unroll
    for (int i = 0; i < 2; ++i)
#pragma unroll
      for (int reg = 0; reg < 4; ++reg) {
        long m = mb + w * 32 + i * 16 + lq * 4 + reg;
        float v = acc[i][j][reg] + bias;
        if (col < C) lseq[m * C + col] = v;
        else if (col == C) hl[m] = v;
      }
  }
}

// ---------------------------------------------------------------------------
// Per-row ACT chain over T halt logits. hlsw: in = halt logits, out = step_w.
__global__ void k_act(float* __restrict__ hlsw, float* __restrict__ out,
                      float* __restrict__ nupb, float* __restrict__ remb) {
  const long b = (long)blockIdx.x * 256 + threadIdx.x;
  float hv[T];
#pragma unroll
  for (int t = 0; t < T; ++t) hv[t] = hlsw[b * T + t];
  float cum = 0.f, rem = 0.f, nu = 0.f;
#pragma unroll
  for (int t = 0; t < T; ++t) {
    float halt = sigmoidf_(hv[t]);
    out[OUT_HALT + b * T + t] = halt;
    float still = (cum < 0.99f) ? 1.f : 0.f;
    float nh = halt * still;
    float would = ((cum + nh) > 0.99f) ? 1.f : 0.f;
    float rema = (1.f - cum) * would * still;
    float swv = nh * (1.f - would) + rema;
    cum += swv; rem += rema; nu += still;
    hlsw[b * T + t] = swv;
  }
  nupb[b] = nu; remb[b] = rem;
}

// ---------------------------------------------------------------------------
// logits[b,c] = b_ro[c] + sum_t sw[b,t]*(lseq[b,t,c]-b_ro[c]);  n_updates copy
__global__ void k_logits(const float* __restrict__ lseq, const float* __restrict__ swb,
                         const float* __restrict__ b_ro, const float* __restrict__ nupb,
                         float* __restrict__ out) {
  const long b = blockIdx.x;
  const int tid = threadIdx.x;
  if (tid < C) {
    float br = b_ro[tid];
    float s = br;
#pragma unroll
    for (int t = 0; t < T; ++t) {
      float sw = swb[b * T + t];
      s = fmaf(sw, lseq[(b * T + t) * C + tid] - br, s);
    }
    out[OUT_LOGITS + b * C + tid] = s;
  } else if (tid == C) {
    out[OUT_NUP + b] = nupb[b];
  }
}

// ---------------------------------------------------------------------------
__global__ void k_ponder(const float* __restrict__ nupb, const float* __restrict__ remb,
                         float* __restrict__ out) {
  __shared__ float sm[4];
  float s = 0.f;
  for (int i = threadIdx.x; i < B; i += 256) s += nupb[i] + remb[i];
#pragma unroll
  for (int m = 1; m < 64; m <<= 1) s += __shfl_xor(s, m, 64);
  int w = threadIdx.x >> 6;
  if ((threadIdx.x & 63) == 0) sm[w] = s;
  __syncthreads();
  if (threadIdx.x == 0)
    out[OUT_PONDER] = (sm[0] + sm[1] + sm[2] + sm[3]) * (1.f / (float)B);
}

// ---------------------------------------------------------------------------
extern "C" void kernel_launch(void* const* d_in, const int* in_sizes, int n_in,
                              void* d_out, int out_size, void* d_ws, size_t ws_size,
                              hipStream_t stream) {
  const float* x      = (const float*)d_in[0];
  const float* W_ih   = (const float*)d_in[1];
  const float* W_hh   = (const float*)d_in[2];
  const float* b_ih   = (const float*)d_in[3];
  const float* b_hh   = (const float*)d_in[4];
  const float* W_halt = (const float*)d_in[5];
  const float* b_halt = (const float*)d_in[6];
  const float* W_ro   = (const float*)d_in[7];
  const float* b_ro   = (const float*)d_in[8];
  float* out = (float*)d_out;
  float* ws  = (float*)d_ws;

  float* xp    = ws + WS_XP;
  ushort* wreg = (ushort*)(ws + WS_W);
  ushort* wih  = wreg;
  ushort* whh  = wreg + 3 * NIH;
  ushort* waug = wreg + 3 * (NIH + NHH);
  float* hlsw  = ws + WS_HL;
  float* nupb  = ws + WS_NUPB;
  float* remb  = ws + WS_REMB;

  k_prep<<<(int)((NIH + 255) / 256), 256, 0, stream>>>(W_ih, W_hh, W_ro, W_halt, wreg);
  k_xproj<<<dim3(B / 128, 4), 256, 0, stream>>>(x, wih, b_ih, xp);
  for (int t = 0; t < T; ++t)
    k_gru<<<dim3(B / 128, 4), 256, 0, stream>>>(whh, xp, b_hh, out, t);
  k_lseq<<<(B * T) / 128, 256, 0, stream>>>(out + OUT_HSEQ, waug, b_ro, b_halt,
                                            out + OUT_LSEQ, hlsw);
  k_act<<<B / 256, 256, 0, stream>>>(hlsw, out, nupb, remb);
  k_logits<<<B, 128, 0, stream>>>(out + OUT_LSEQ, hlsw, b_ro, nupb, out);
  k_ponder<<<1, 256, 0, stream>>>(nupb, remb, out);
}

// Round 3
// 2495.751 us; speedup vs baseline: 2.1440x; 1.1972x over previous
//
#include <hip/hip_runtime.h>
#include <cmath>

// ---------------------------------------------------------------------------
// ACT classifier (B=65536, D=512, H=256, C=100, T=10).
// Round 3: f16 2-split (3 MFMA products, half of round 2's 6) with 2^8
// operand pre-scaling so split residuals stay out of the f16-subnormal range
// (robust to MFMA denormal flushing). Halt logits computed fp32-exact in the
// GRU epilogue (shuffle+LDS+fixed-order strip sum) instead of via MFMA.
// Readout GEMM single-product f16 (logits tolerance 0.08 >> 1e-4 error).
// XCD-aware swizzle keeps the 4 col-strips of a row-tile on one XCD's L2.
// ---------------------------------------------------------------------------

namespace {
constexpr int B = 65536, D = 512, H = 256, C = 100, T = 10;

// output layout (flat float elements, reference return order)
constexpr long OUT_LOGITS = 0;
constexpr long OUT_PONDER = (long)B * C;
constexpr long OUT_NUP    = OUT_PONDER + 1;
constexpr long OUT_HSEQ   = OUT_NUP + B;
constexpr long OUT_HALT   = OUT_HSEQ + (long)B * T * H;
constexpr long OUT_LSEQ   = OUT_HALT + (long)B * T;

// weight plane sizes (elements)
constexpr long NIH  = 768L * D;   // 393216
constexpr long NHH  = 768L * H;   // 196608
constexpr long NAUG = 112L * H;   // 28672

// workspace layout (float units) — total 51,998,720 floats (<208 MB)
constexpr long WS_XP   = 0;                          // x_proj [B][768] f32
constexpr long WS_W16  = WS_XP + (long)B * 768;      // f16 planes (2x each W)
constexpr long W_HALV  = 2 * (NIH + NHH + NAUG);     // 1,236,992 halves
constexpr long WS_HL   = WS_W16 + (W_HALV + 1) / 2;  // step_w [B][T]
constexpr long WS_HP4  = WS_HL + (long)B * T;        // halt partials [4][B]
constexpr long WS_NUPB = WS_HP4 + 4L * B;
constexpr long WS_REMB = WS_NUPB + B;

constexpr float SC = 256.f;            // operand pre-scale 2^8
constexpr float SB = 1.f / 65536.f;    // product scale-back 2^-16 (exact)
} // namespace

typedef __attribute__((ext_vector_type(8))) _Float16 h8;
typedef __attribute__((ext_vector_type(4))) _Float16 h4;
typedef __attribute__((ext_vector_type(4))) float f4;

#define MFMA16(A, Bo, Cc) __builtin_amdgcn_mfma_f32_16x16x32_f16(A, Bo, Cc, 0, 0, 0)
// 3-product 2-split accumulate, smallest first
#define PROD3(a, Ah, Al, Bh, Bl)                                               \
  a = MFMA16(Al, Bh, a);                                                       \
  a = MFMA16(Ah, Bl, a);                                                       \
  a = MFMA16(Ah, Bh, a);

__device__ __forceinline__ float sigmoidf_(float x) {
  if (x >= 0.f) { return 1.f / (1.f + expf(-x)); }
  float e = expf(x);
  return e / (1.f + e);
}

// ---------------------------------------------------------------------------
// split weights (pre-scaled by 2^8) into f16 hi/lo planes
__global__ void k_prep(const float* __restrict__ wih_s, const float* __restrict__ whh_s,
                       const float* __restrict__ wro, const float* __restrict__ whalt,
                       _Float16* __restrict__ wr) {
  long idx = (long)blockIdx.x * 256 + threadIdx.x;
  if (idx < NIH) {
    float xs = wih_s[idx] * SC;
    _Float16 h = (_Float16)xs;
    _Float16 l = (_Float16)(xs - (float)h);
    wr[idx] = h; wr[NIH + idx] = l;
  }
  if (idx < NHH) {
    float xs = whh_s[idx] * SC;
    _Float16 h = (_Float16)xs;
    _Float16 l = (_Float16)(xs - (float)h);
    long b = 2 * NIH;
    wr[b + idx] = h; wr[b + NHH + idx] = l;
  }
  if (idx < NAUG) {
    int row = (int)(idx >> 8), k = (int)(idx & 255);
    float x = (row < C) ? wro[row * 256 + k] : ((row == C) ? whalt[k] : 0.f);
    float xs = x * SC;
    _Float16 h = (_Float16)xs;
    _Float16 l = (_Float16)(xs - (float)h);
    long b = 2 * (NIH + NHH);
    wr[b + idx] = h; wr[b + NAUG + idx] = l;
  }
}

// stage 16 fp32 elems (scaled) as f16 hi/lo into LDS at row*40+kk0
__device__ __forceinline__ void stageA16(const float* __restrict__ src,
                                         _Float16* As0, _Float16* As1,
                                         int o) {
#pragma unroll
  for (int i = 0; i < 4; ++i) {
    float4 v = ((const float4*)src)[i];
    float vv[4] = {v.x, v.y, v.z, v.w};
    h4 hh, ll;
#pragma unroll
    for (int c = 0; c < 4; ++c) {
      float sv = vv[c] * SC;
      _Float16 h = (_Float16)sv;
      hh[c] = h;
      ll[c] = (_Float16)(sv - (float)h);
    }
    *(h4*)&As0[o + i * 4] = hh;
    *(h4*)&As1[o + i * 4] = ll;
  }
}

// ---------------------------------------------------------------------------
// xp = x @ W_ih^T + b_ih.  Grid 2048 (XCD-swizzled: 512 row-tiles x 4 strips).
__global__ __launch_bounds__(256, 2) void k_xproj(
    const float* __restrict__ x, const _Float16* __restrict__ wih,
    const float* __restrict__ b_ih, float* __restrict__ xp) {
  __shared__ __align__(16) _Float16 As0[128 * 40], As1[128 * 40];
  __shared__ __align__(16) _Float16 Bs0[192 * 40], Bs1[192 * 40];
  const int tid = threadIdx.x;
  const int w = tid >> 6, l = tid & 63;
  const int lr = l & 15, lq = l >> 4;
  const int bid = blockIdx.x;
  const int gid = (bid & 7) * 256 + (bid >> 3);   // XCD-contiguous
  const int c0 = (gid & 3) * 64;
  const int rb = (gid >> 2) * 128;

  f4 acc[8][3];
#pragma unroll
  for (int i = 0; i < 8; ++i)
#pragma unroll
    for (int g = 0; g < 3; ++g) acc[i][g] = (f4)0.f;

  for (int kc = 0; kc < 16; ++kc) {
    const int k0 = kc * 32;
    __syncthreads();
    {  // stage A (x rows, scaled split)
      const int row = tid >> 1, kk0 = (tid & 1) * 16;
      stageA16(x + (long)(rb + row) * D + k0 + kk0, As0, As1, row * 40 + kk0);
    }
#pragma unroll
    for (int it = 0; it < 3; ++it) {  // stage B
      int idx = tid + it * 256;  // < 768
      int scol = idx >> 2, kg = idx & 3;
      int gcol = (scol >> 6) * 256 + c0 + (scol & 63);
      *(h8*)&Bs0[scol * 40 + kg * 8] = *(const h8*)(wih + (long)gcol * D + k0 + kg * 8);
      *(h8*)&Bs1[scol * 40 + kg * 8] = *(const h8*)(wih + NIH + (long)gcol * D + k0 + kg * 8);
    }
    __syncthreads();
    h8 Bh[3], Bl[3];
#pragma unroll
    for (int g = 0; g < 3; ++g) {
      Bh[g] = *(const h8*)&Bs0[(g * 64 + w * 16 + lr) * 40 + lq * 8];
      Bl[g] = *(const h8*)&Bs1[(g * 64 + w * 16 + lr) * 40 + lq * 8];
    }
#pragma unroll
    for (int i = 0; i < 8; ++i) {
      h8 Ah = *(const h8*)&As0[(i * 16 + lr) * 40 + lq * 8];
      h8 Al = *(const h8*)&As1[(i * 16 + lr) * 40 + lq * 8];
#pragma unroll
      for (int g = 0; g < 3; ++g) { PROD3(acc[i][g], Ah, Al, Bh[g], Bl[g]); }
    }
  }
  const int ch = c0 + w * 16 + lr;
  float bi[3] = {b_ih[ch], b_ih[256 + ch], b_ih[512 + ch]};
#pragma unroll
  for (int i = 0; i < 8; ++i)
#pragma unroll
    for (int g = 0; g < 3; ++g)
#pragma unroll
      for (int reg = 0; reg < 4; ++reg) {
        long row = rb + i * 16 + lq * 4 + reg;
        xp[row * 768 + g * 256 + ch] = fmaf(acc[i][g][reg], SB, bi[g]);
      }
}

// ---------------------------------------------------------------------------
// One GRU step + fp32-exact halt partial dot per 64-col strip.
__global__ __launch_bounds__(256, 2) void k_gru(
    const _Float16* __restrict__ whh, const float* __restrict__ xp,
    const float* __restrict__ b_hh, const float* __restrict__ w_halt,
    float* __restrict__ out, float* __restrict__ hp4, int t) {
  __shared__ __align__(16) _Float16 As0[128 * 40], As1[128 * 40];
  __shared__ __align__(16) _Float16 Bs0[192 * 40], Bs1[192 * 40];
  __shared__ float lds_hp[128][4];
  const int tid = threadIdx.x;
  const int w = tid >> 6, l = tid & 63;
  const int lr = l & 15, lq = l >> 4;
  const int bid = blockIdx.x;
  const int gid = (bid & 7) * 256 + (bid >> 3);
  const int strip = gid & 3;
  const int c0 = strip * 64;
  const int rb = (gid >> 2) * 128;

  f4 acc[8][3];
#pragma unroll
  for (int i = 0; i < 8; ++i)
#pragma unroll
    for (int g = 0; g < 3; ++g) acc[i][g] = (f4)0.f;

  if (t > 0) {
    for (int kc = 0; kc < 8; ++kc) {
      const int k0 = kc * 32;
      __syncthreads();
      {  // stage A = h_{t-1}
        const int row = tid >> 1, kk0 = (tid & 1) * 16;
        stageA16(out + OUT_HSEQ + (long)(rb + row) * (T * H) + (long)(t - 1) * H + k0 + kk0,
                 As0, As1, row * 40 + kk0);
      }
#pragma unroll
      for (int it = 0; it < 3; ++it) {  // stage B (W_hh planes)
        int idx = tid + it * 256;
        int scol = idx >> 2, kg = idx & 3;
        int gcol = (scol >> 6) * 256 + c0 + (scol & 63);
        *(h8*)&Bs0[scol * 40 + kg * 8] = *(const h8*)(whh + (long)gcol * H + k0 + kg * 8);
        *(h8*)&Bs1[scol * 40 + kg * 8] = *(const h8*)(whh + NHH + (long)gcol * H + k0 + kg * 8);
      }
      __syncthreads();
      h8 Bh[3], Bl[3];
#pragma unroll
      for (int g = 0; g < 3; ++g) {
        Bh[g] = *(const h8*)&Bs0[(g * 64 + w * 16 + lr) * 40 + lq * 8];
        Bl[g] = *(const h8*)&Bs1[(g * 64 + w * 16 + lr) * 40 + lq * 8];
      }
#pragma unroll
      for (int i = 0; i < 8; ++i) {
        h8 Ah = *(const h8*)&As0[(i * 16 + lr) * 40 + lq * 8];
        h8 Al = *(const h8*)&As1[(i * 16 + lr) * 40 + lq * 8];
#pragma unroll
        for (int g = 0; g < 3; ++g) { PROD3(acc[i][g], Ah, Al, Bh[g], Bl[g]); }
      }
    }
  }

  // epilogue: gates + h_new + halt partial
  const int ch = c0 + w * 16 + lr;
  const float bhr = b_hh[ch], bhz = b_hh[256 + ch], bhn = b_hh[512 + ch];
  const float whv = w_halt[ch];
#pragma unroll
  for (int i = 0; i < 8; ++i)
#pragma unroll
    for (int reg = 0; reg < 4; ++reg) {
      const int rloc = i * 16 + lq * 4 + reg;
      const long row = rb + rloc;
      float xr = xp[row * 768 + ch];
      float xz = xp[row * 768 + 256 + ch];
      float xn = xp[row * 768 + 512 + ch];
      float ho = (t > 0) ? out[OUT_HSEQ + row * (T * H) + (long)(t - 1) * H + ch] : 0.f;
      float rr = sigmoidf_(xr + fmaf(acc[i][0][reg], SB, bhr));
      float zz = sigmoidf_(xz + fmaf(acc[i][1][reg], SB, bhz));
      float nn = tanhf(xn + rr * fmaf(acc[i][2][reg], SB, bhn));
      float hv = (1.f - zz) * nn + zz * ho;
      out[OUT_HSEQ + row * (T * H) + (long)t * H + ch] = hv;
      // halt partial over this wave's 16 cols (fp32 shuffle tree)
      float p = hv * whv;
#pragma unroll
      for (int m = 1; m < 16; m <<= 1) p += __shfl_xor(p, m, 64);
      if (lr == 0) lds_hp[rloc][w] = p;
    }
  __syncthreads();
  if (tid < 128)
    hp4[(long)strip * B + rb + tid] =
        ((lds_hp[tid][0] + lds_hp[tid][1]) + (lds_hp[tid][2] + lds_hp[tid][3]));
}

// ---------------------------------------------------------------------------
// halt[b,t] = sigmoid(b_halt + sum of 4 strip partials), fixed order.
__global__ void k_sumhp(const float* __restrict__ hp4, const float* __restrict__ b_halt,
                        float* __restrict__ out, int t) {
  const long b = (long)blockIdx.x * 256 + threadIdx.x;
  float v = b_halt[0] + hp4[b] + hp4[B + b] + hp4[2L * B + b] + hp4[3L * B + b];
  out[OUT_HALT + b * T + t] = sigmoidf_(v);
}

// ---------------------------------------------------------------------------
// Readout: [B*T,256] x [256,112] single-product f16 (cols 0..99 kept).
__global__ __launch_bounds__(256, 4) void k_lseq(
    const float* __restrict__ hseq, const _Float16* __restrict__ waug,
    const float* __restrict__ b_ro, float* __restrict__ lseq) {
  __shared__ __align__(16) _Float16 As0[128 * 40];
  __shared__ __align__(16) _Float16 Bs0[112 * 40];
  const int tid = threadIdx.x;
  const int w = tid >> 6, l = tid & 63;
  const int lr = l & 15, lq = l >> 4;
  const long mb = (long)blockIdx.x * 128;

  f4 acc[2][7];
#pragma unroll
  for (int i = 0; i < 2; ++i)
#pragma unroll
    for (int j = 0; j < 7; ++j) acc[i][j] = (f4)0.f;

  for (int kc = 0; kc < 8; ++kc) {
    const int k0 = kc * 32;
    __syncthreads();
    {  // stage A hi-plane only
      const int row = tid >> 1, kk0 = (tid & 1) * 16;
      const float* src = hseq + (mb + row) * H + k0 + kk0;
      const int o = row * 40 + kk0;
#pragma unroll
      for (int i = 0; i < 4; ++i) {
        float4 v = ((const float4*)src)[i];
        h4 hh;
        hh[0] = (_Float16)(v.x * SC); hh[1] = (_Float16)(v.y * SC);
        hh[2] = (_Float16)(v.z * SC); hh[3] = (_Float16)(v.w * SC);
        *(h4*)&As0[o + i * 4] = hh;
      }
    }
#pragma unroll
    for (int it = 0; it < 2; ++it) {  // stage B hi-plane
      int idx = tid + it * 256;
      if (idx < 448) {
        int scol = idx >> 2, kg = idx & 3;
        *(h8*)&Bs0[scol * 40 + kg * 8] = *(const h8*)(waug + (long)scol * H + k0 + kg * 8);
      }
    }
    __syncthreads();
    h8 Af[2];
#pragma unroll
    for (int i = 0; i < 2; ++i)
      Af[i] = *(const h8*)&As0[(w * 32 + i * 16 + lr) * 40 + lq * 8];
#pragma unroll
    for (int j = 0; j < 7; ++j) {
      h8 Bf = *(const h8*)&Bs0[(j * 16 + lr) * 40 + lq * 8];
#pragma unroll
      for (int i = 0; i < 2; ++i) acc[i][j] = MFMA16(Af[i], Bf, acc[i][j]);
    }
  }
#pragma unroll
  for (int j = 0; j < 7; ++j) {
    const int col = j * 16 + lr;
    if (col < C) {
      const float br = b_ro[col];
#pragma unroll
      for (int i = 0; i < 2; ++i)
#pragma unroll
        for (int reg = 0; reg < 4; ++reg) {
          long m = mb + w * 32 + i * 16 + lq * 4 + reg;
          lseq[m * C + col] = fmaf(acc[i][j][reg], SB, br);
        }
    }
  }
}

// ---------------------------------------------------------------------------
// Per-row ACT chain: reads halt_seq (already in out), writes step_w + stats.
__global__ void k_act(const float* __restrict__ out_halt, float* __restrict__ swb,
                      float* __restrict__ nupb, float* __restrict__ remb) {
  const long b = (long)blockIdx.x * 256 + threadIdx.x;
  float cum = 0.f, rem = 0.f, nu = 0.f;
#pragma unroll
  for (int t = 0; t < T; ++t) {
    float halt = out_halt[b * T + t];
    float still = (cum < 0.99f) ? 1.f : 0.f;
    float nh = halt * still;
    float would = ((cum + nh) > 0.99f) ? 1.f : 0.f;
    float rema = (1.f - cum) * would * still;
    float swv = nh * (1.f - would) + rema;
    cum += swv; rem += rema; nu += still;
    swb[b * T + t] = swv;
  }
  nupb[b] = nu; remb[b] = rem;
}

// ---------------------------------------------------------------------------
__global__ void k_logits(const float* __restrict__ lseq, const float* __restrict__ swb,
                         const float* __restrict__ b_ro, const float* __restrict__ nupb,
                         float* __restrict__ out) {
  const long b = blockIdx.x;
  const int tid = threadIdx.x;
  if (tid < C) {
    float br = b_ro[tid];
    float s = br;
#pragma unroll
    for (int t = 0; t < T; ++t) {
      float sw = swb[b * T + t];
      s = fmaf(sw, lseq[(b * T + t) * C + tid] - br, s);
    }
    out[OUT_LOGITS + b * C + tid] = s;
  } else if (tid == C) {
    out[OUT_NUP + b] = nupb[b];
  }
}

// ---------------------------------------------------------------------------
__global__ void k_ponder(const float* __restrict__ nupb, const float* __restrict__ remb,
                         float* __restrict__ out) {
  __shared__ float sm[4];
  float s = 0.f;
  for (int i = threadIdx.x; i < B; i += 256) s += nupb[i] + remb[i];
#pragma unroll
  for (int m = 1; m < 64; m <<= 1) s += __shfl_xor(s, m, 64);
  int w = threadIdx.x >> 6;
  if ((threadIdx.x & 63) == 0) sm[w] = s;
  __syncthreads();
  if (threadIdx.x == 0)
    out[OUT_PONDER] = (sm[0] + sm[1] + sm[2] + sm[3]) * (1.f / (float)B);
}

// ---------------------------------------------------------------------------
extern "C" void kernel_launch(void* const* d_in, const int* in_sizes, int n_in,
                              void* d_out, int out_size, void* d_ws, size_t ws_size,
                              hipStream_t stream) {
  const float* x      = (const float*)d_in[0];
  const float* W_ih   = (const float*)d_in[1];
  const float* W_hh   = (const float*)d_in[2];
  const float* b_ih   = (const float*)d_in[3];
  const float* b_hh   = (const float*)d_in[4];
  const float* W_halt = (const float*)d_in[5];
  const float* b_halt = (const float*)d_in[6];
  const float* W_ro   = (const float*)d_in[7];
  const float* b_ro   = (const float*)d_in[8];
  float* out = (float*)d_out;
  float* ws  = (float*)d_ws;

  float* xp        = ws + WS_XP;
  _Float16* w16    = (_Float16*)(ws + WS_W16);
  _Float16* wih16  = w16;
  _Float16* whh16  = w16 + 2 * NIH;
  _Float16* waug16 = w16 + 2 * (NIH + NHH);
  float* swb  = ws + WS_HL;
  float* hp4  = ws + WS_HP4;
  float* nupb = ws + WS_NUPB;
  float* remb = ws + WS_REMB;

  k_prep<<<(int)((NIH + 255) / 256), 256, 0, stream>>>(W_ih, W_hh, W_ro, W_halt, w16);
  k_xproj<<<2048, 256, 0, stream>>>(x, wih16, b_ih, xp);
  for (int t = 0; t < T; ++t) {
    k_gru<<<2048, 256, 0, stream>>>(whh16, xp, b_hh, W_halt, out, hp4, t);
    k_sumhp<<<B / 256, 256, 0, stream>>>(hp4, b_halt, out, t);
  }
  k_lseq<<<(B * T) / 128, 256, 0, stream>>>(out + OUT_HSEQ, waug16, b_ro, out + OUT_LSEQ);
  k_act<<<B / 256, 256, 0, stream>>>(out + OUT_HALT, swb, nupb, remb);
  k_logits<<<B, 128, 0, stream>>>(out + OUT_LSEQ, swb, b_ro, nupb, out);
  k_ponder<<<1, 256, 0, stream>>>(nupb, remb, out);
}